// Round 3
// baseline (742.767 us; speedup 1.0000x reference)
//
#include <hip/hip_runtime.h>
#include <stdint.h>

// Inputs/outputs fp32; internal compute bf16 MFMA + fp32 accumulate.
// B=4 S=2048 D=1024 H=16 DH=64 F=4096; M = B*S = 8192.

typedef short bf16x8 __attribute__((ext_vector_type(8)));
typedef unsigned short u16x8 __attribute__((ext_vector_type(8)));
typedef float f32x4 __attribute__((ext_vector_type(4)));
typedef unsigned int u32x2 __attribute__((ext_vector_type(2)));

#define MFMA16(a, b, c) __builtin_amdgcn_mfma_f32_16x16x32_bf16((a), (b), (c), 0, 0, 0)

// 0.125 (1/sqrt(64)) / ln(2): folded into Q so softmax runs in exp2 domain.
#define QSCALE 0.1803368801111204f

__device__ __forceinline__ float b2f(unsigned short u) {
    union { unsigned u32; float f; } x;
    x.u32 = ((unsigned)u) << 16;
    return x.f;
}
__device__ __forceinline__ unsigned short f2b(float f) {
    union { float f; unsigned u; } x;
    x.f = f;
    unsigned r = x.u + 0x7fff + ((x.u >> 16) & 1);  // RNE
    return (unsigned short)(r >> 16);
}
// pack 2 fp32 -> 2 bf16 (round-half-up) in one dword: 2 add + 1 v_perm
__device__ __forceinline__ unsigned pack2(float lo, float hi) {
    union { float f; unsigned u; } a, b;
    a.f = lo; b.f = hi;
    return __builtin_amdgcn_perm(b.u + 0x8000u, a.u + 0x8000u, 0x07060302u);
}

// async 16B global -> LDS (wave-uniform LDS base + lane*16 dest semantics)
__device__ __forceinline__ void gl16(const unsigned short* g, unsigned short* l) {
    __builtin_amdgcn_global_load_lds(
        (__attribute__((address_space(1))) unsigned int*)(unsigned long)g,
        (__attribute__((address_space(3))) unsigned int*)l, 16, 0, 0);
}

// ---------------------------------------------------------------------------
// fp32 -> bf16 bulk convert (8 elems/thread)
// ---------------------------------------------------------------------------
__global__ __launch_bounds__(256) void f2b_bulk(const float* __restrict__ in,
                                                unsigned short* __restrict__ out) {
    const long i = ((long)blockIdx.x * 256 + threadIdx.x) * 8;
    float4 a = *(const float4*)&in[i];
    float4 b = *(const float4*)&in[i + 4];
    u16x8 u;
    u[0] = f2b(a.x); u[1] = f2b(a.y); u[2] = f2b(a.z); u[3] = f2b(a.w);
    u[4] = f2b(b.x); u[5] = f2b(b.y); u[6] = f2b(b.z); u[7] = f2b(b.w);
    *(u16x8*)&out[i] = u;
}

// ---------------------------------------------------------------------------
// Tiled transpose fp32 -> bf16: out[(row0+batch*C+c)*out_ld + r] = in[b][r][c]
// ---------------------------------------------------------------------------
__global__ void transpose_f2b(const float* __restrict__ in,
                              unsigned short* __restrict__ out,
                              int R, int C, long in_batch_stride,
                              int out_row0, int out_ld) {
    __shared__ float tile[32][33];
    const int batch = blockIdx.z;
    const float* src = in + (long)batch * in_batch_stride;
    const int c0 = blockIdx.x * 32, r0 = blockIdx.y * 32;
    const int tx = threadIdx.x, ty = threadIdx.y;  // (32, 8)
#pragma unroll
    for (int i = 0; i < 32; i += 8)
        tile[ty + i][tx] = src[(long)(r0 + ty + i) * C + c0 + tx];
    __syncthreads();
#pragma unroll
    for (int i = 0; i < 32; i += 8)
        out[(long)(out_row0 + batch * C + c0 + ty + i) * out_ld + r0 + tx] =
            f2b(tile[tx][ty + i]);
}

// ---------------------------------------------------------------------------
// V^T builder: vt[(bh*64 + e)*2048 + s] = qkv[(b*2048+s)*3072 + 2048 + h*64 + e]
// ---------------------------------------------------------------------------
__global__ void transpose_v(const unsigned short* __restrict__ qkv,
                            unsigned short* __restrict__ vt) {
    __shared__ unsigned short tile[32][33];
    const int bh = blockIdx.z;
    const int b = bh >> 4, h = bh & 15;
    const int s0 = blockIdx.x * 32, e0 = blockIdx.y * 32;
    const int tx = threadIdx.x, ty = threadIdx.y;  // (32, 8)
    const unsigned short* src = qkv + ((long)b * 2048) * 3072 + 2048 + h * 64;
#pragma unroll
    for (int i = 0; i < 32; i += 8)
        tile[ty + i][tx] = src[(long)(s0 + ty + i) * 3072 + e0 + tx];
    __syncthreads();
    unsigned short* dst = vt + ((long)bh * 64) * 2048;
#pragma unroll
    for (int i = 0; i < 32; i += 8)
        dst[(long)(e0 + ty + i) * 2048 + s0 + tx] = tile[tx][ty + i];
}

__global__ void concat_bias(const float* __restrict__ bq,
                            const float* __restrict__ bk,
                            const float* __restrict__ bv,
                            float* __restrict__ out) {
    int n = blockIdx.x * 256 + threadIdx.x;  // 0..3071
    out[n] = (n < 1024) ? bq[n] : (n < 2048) ? bk[n - 1024] : bv[n - 2048];
}

__device__ __forceinline__ float to_f(float v) { return v; }
__device__ __forceinline__ float to_f(unsigned short v) { return b2f(v); }

// ---------------------------------------------------------------------------
// C[M,N] = A[M,K] @ Bt[N,K]^T (bf16), fp32 accum, bf16 out.
// BK=64 variant: LDS holds two back-to-back [128][32] k-half buffers per
// operand (32 KB total). Doubles per-iteration work so the barrier's vmcnt
// drain (~200-900 cyc) is covered by co-resident blocks; halves barrier
// count vs BK=32. Staging stays 1KB-contiguous gl16; fragment reads keep
// m97's [128][32] conflict profile.
// op: 0 none, 1 ReLU, 2 scale cols<1024 by QSCALE (QKV gemm: pre-scale Q).
// ---------------------------------------------------------------------------
template <typename RT>
__global__ __launch_bounds__(256) void gemm_bt(
    const unsigned short* __restrict__ A, const unsigned short* __restrict__ Bt,
    unsigned short* __restrict__ C, const float* __restrict__ bias,
    const RT* __restrict__ resid, int M, int N, int K, int op) {
    __shared__ __align__(16) unsigned short As[2 * 128 * 32];  // 16 KB
    __shared__ __align__(16) unsigned short Bs[2 * 128 * 32];  // 16 KB
    const int tid = threadIdx.x;
    const int wave = tid >> 6, lane = tid & 63;
    const int quad = lane >> 4, lr = lane & 15;
    const int wm = (wave >> 1) << 6, wn = (wave & 1) << 6;
    const long m0 = (long)blockIdx.y * 128;
    const long n0 = (long)blockIdx.x * 128;

    f32x4 acc[4][4] = {};

    // staging: wave w stages rows [w*32, w*32+32) x 64 cols as two k-half
    // blocks. Per gl16: 16 rows x 32 cols (1KB); lane row = lane>>2,
    // col = (lane&3)*8.
    const int srow = wave * 32 + (lane >> 2);
    const int scol = (lane & 3) * 8;
    const unsigned short* ga = A + (m0 + srow) * (long)K + scol;
    const unsigned short* gb = Bt + (n0 + srow) * (long)K + scol;
    unsigned short* la = &As[wave * 32 * 32];
    unsigned short* lb = &Bs[wave * 32 * 32];
    const long rstep = 16 * (long)K;

    for (int k0 = 0; k0 < K; k0 += 64) {
        gl16(ga + k0, la);                              // kh0 rows 0-15
        gl16(ga + k0 + rstep, la + 512);                // kh0 rows 16-31
        gl16(ga + k0 + 32, la + 4096);                  // kh1 rows 0-15
        gl16(ga + k0 + 32 + rstep, la + 4096 + 512);    // kh1 rows 16-31
        gl16(gb + k0, lb);
        gl16(gb + k0 + rstep, lb + 512);
        gl16(gb + k0 + 32, lb + 4096);
        gl16(gb + k0 + 32 + rstep, lb + 4096 + 512);
        __syncthreads();
#pragma unroll
        for (int kh = 0; kh < 2; kh++) {
            const int kb = kh * 4096;
            bf16x8 af[4], bfr[4];
#pragma unroll
            for (int mi = 0; mi < 4; mi++)
                af[mi] = *(const bf16x8*)&As[kb + (wm + mi * 16 + lr) * 32 + quad * 8];
#pragma unroll
            for (int ni = 0; ni < 4; ni++)
                bfr[ni] = *(const bf16x8*)&Bs[kb + (wn + ni * 16 + lr) * 32 + quad * 8];
#pragma unroll
            for (int mi = 0; mi < 4; mi++)
#pragma unroll
                for (int ni = 0; ni < 4; ni++)
                    acc[mi][ni] = MFMA16(af[mi], bfr[ni], acc[mi][ni]);
        }
        __syncthreads();
    }

#pragma unroll
    for (int ni = 0; ni < 4; ni++) {
        const long col = n0 + wn + ni * 16 + lr;
        const float bv = bias ? bias[col] : 0.0f;
        const float cscale = (op == 2 && col < 1024) ? QSCALE : 1.0f;
#pragma unroll
        for (int mi = 0; mi < 4; mi++) {
#pragma unroll
            for (int r = 0; r < 4; r++) {
                const long row = m0 + wm + mi * 16 + quad * 4 + r;
                float v = (acc[mi][ni][r] + bv) * cscale;
                if (resid) v += to_f(resid[row * (long)N + col]);
                if (op == 1) v = fmaxf(v, 0.0f);
                C[row * (long)N + col] = f2b(v);
            }
        }
    }
}

// ---------------------------------------------------------------------------
// Flash attention v8 (transposed-S; NO-MAX softmax; in-register P^T
// redistribution; ones-MFMA denominator).
// v7 -> v8: V is no longer LDS-staged. Rationale: per-iter compute (~350
// cyc) is shorter than the staging HBM latency the end-of-iter barrier
// drains (vmcnt(0), ~500-900 cyc), so every block stalls each iteration
// and 5 blocks/CU (LDS 32 KB) can't cover it. Each (b,h)'s V^T tile is
// 256 KB and the XCD block swizzle pins all 32 q-blocks of a (b,h) to one
// XCD -> V is L2-resident; the PV A-fragment global read is fully
// coalesced (16 rows x 64 B per nt). Dropping Vlds:
//   LDS 32768 -> 16384 B  => 8 blocks/CU (32 waves = HW max; entire 2048-
//   block grid co-resident), STAGE halves (2 gl16), barrier drain shorter.
// __launch_bounds__(256,8) caps VGPR at 64 so occupancy stays 8 blocks.
// ---------------------------------------------------------------------------
__global__ __launch_bounds__(256, 8) void attn_kernel(
    const unsigned short* __restrict__ qkv, const unsigned short* __restrict__ vt,
    unsigned short* __restrict__ o) {
    __shared__ __align__(16) unsigned short Klds[2][64 * 64];  // 16 KB
    // Block swizzle: all 32 q-tiles of one (b,h) share l%8 -> same XCD.
    const int l = blockIdx.x;
    const int bh = ((l >> 8) << 3) | (l & 7);
    const int qt = (l >> 3) & 31;
    const int b = bh >> 4, h = bh & 15;
    const int tid = threadIdx.x;
    const int wave = tid >> 6, lane = tid & 63;
    const int quad = lane >> 4, lr = lane & 15;
    const long rowbase = (long)b * 2048;
    const int qb = qt * 64 + wave * 16;

    // Q fragments (B operand; n = query = lr), register-resident
    bf16x8 q0, q1;
    {
        const unsigned short* qrow = qkv + (rowbase + qb + lr) * 3072 + h * 64;
        q0 = *(const bf16x8*)&qrow[quad * 8];
        q1 = *(const bf16x8*)&qrow[32 + quad * 8];
    }

    // all-ones bf16 A-fragment for the denominator MFMA
    bf16x8 ones;
#pragma unroll
    for (int i = 0; i < 8; i++) ones[i] = (short)0x3F80;

    // K staging: wave w stages rows [w*16, w*16+16) of the K tile via 2 gl16.
    // Lane: row = base + (lane>>3), dst chunk = lane&7,
    // src chunk = (lane&7) ^ (row&7)  [row&7 == lane>>3 here].
    const int srow = lane >> 3;
    const int sxc = (lane & 7) ^ srow;
    const unsigned short* kp =
        qkv + (rowbase + wave * 16 + srow) * 3072 + 1024 + h * 64 + sxc * 8;
    const long KADV = 64L * 3072;  // next key-tile (rows)
    unsigned short* const kd0 = &Klds[0][wave * 16 * 64];

    // V^T per-lane fragment base (global, L2-resident):
    // va(nt,kc,kt) = vt[(bh*64 + nt*16 + lr)*2048 + kt*64 + kc*32 + quad*8]
    const unsigned short* vg = vt + ((long)bh * 64 + lr) * 2048 + quad * 8;

#define STAGE(bf)                                                     \
    {                                                                 \
        gl16(kp, kd0 + (bf)*4096);                                    \
        gl16(kp + 8 * 3072, kd0 + (bf)*4096 + 8 * 64);                \
    }

    f32x4 oacc[4] = {};
    f32x4 dacc = {};  // denominator accumulator (all rows identical)

    // swizzled chunk offsets for K A-operand reads (row&7 == lr&7)
    const int x7 = lr & 7;
    const int c00 = (quad ^ x7) * 8;        // kc=0
    const int c01 = ((4 | quad) ^ x7) * 8;  // kc=1

    STAGE(0);
    __syncthreads();

    for (int kt = 0; kt < 32; kt++) {
        const int buf = kt & 1;
        if (kt < 31) {
            kp += KADV;
            STAGE(buf ^ 1);
        }
        // S^T = K·Q^T  (A = K tile rows, k-dim = dh)
        const unsigned short* kb = &Klds[buf][0];
        f32x4 s4[4];
#pragma unroll
        for (int nt = 0; nt < 4; nt++) {
            const unsigned short* krow = kb + (nt * 16 + lr) * 64;
            bf16x8 k0 = *(const bf16x8*)&krow[c00];
            bf16x8 k1 = *(const bf16x8*)&krow[c01];
            f32x4 z = {};
            z = MFMA16(k0, q0, z);
            z = MFMA16(k1, q1, z);
            s4[nt] = z;
        }
        // p = exp2(s) unnormalized; pack pairs to bf16 (v_cvt_pk, RNE).
        // pwv[nt][tl] holds keys (nt*16 + quad*4 + 2*tl, +1) for query lr.
        unsigned pwv[4][2];
#pragma unroll
        for (int nt = 0; nt < 4; nt++) {
            float p0 = exp2f(s4[nt][0]);
            float p1 = exp2f(s4[nt][1]);
            float p2 = exp2f(s4[nt][2]);
            float p3 = exp2f(s4[nt][3]);
            asm("v_cvt_pk_bf16_f32 %0, %1, %2"
                : "=v"(pwv[nt][0]) : "v"(p0), "v"(p1));
            asm("v_cvt_pk_bf16_f32 %0, %1, %2"
                : "=v"(pwv[nt][1]) : "v"(p2), "v"(p3));
        }
        // In-register P^T quad redistribution (permlane swaps).
        // Stage 1: pairs over reg-bit k4 = nt&1: permlane32_swap.
        // Stage 2: pairs over reg-bit k3: permlane16_swap.
        // Result pq[kc][t]: keys (kc*32 + quad*8 + 2t, +1) for query lr —
        // exactly the 16x16x32 B-operand fragment for PV.
        unsigned pq[2][4];
#pragma unroll
        for (int kc = 0; kc < 2; kc++)
#pragma unroll
            for (int tl = 0; tl < 2; tl++) {
                u32x2 y = __builtin_amdgcn_permlane32_swap(
                    pwv[2 * kc][tl], pwv[2 * kc + 1][tl], false, false);
                u32x2 z = __builtin_amdgcn_permlane16_swap(y[0], y[1], false, false);
                pq[kc][tl] = z[0];
                pq[kc][2 + tl] = z[1];
            }

        // O^T += V^T·P^T  (A = V^T fragments from global/L2, k-dim = keys)
        // + denominator row-sum on the matrix pipe (A = ones).
        const unsigned short* vk = vg + kt * 64;
#pragma unroll
        for (int kc = 0; kc < 2; kc++) {
            union { unsigned u[4]; bf16x8 h; } pu;
            pu.u[0] = pq[kc][0]; pu.u[1] = pq[kc][1];
            pu.u[2] = pq[kc][2]; pu.u[3] = pq[kc][3];
            dacc = MFMA16(ones, pu.h, dacc);
#pragma unroll
            for (int nt = 0; nt < 4; nt++) {
                bf16x8 va = *(const bf16x8*)&vk[nt * 16 * 2048 + kc * 32];
                oacc[nt] = MFMA16(va, pu.h, oacc[nt]);
            }
        }
        __syncthreads();  // Klds buf readers done + buf^1 staging drained
    }

    // dacc rows are identical: dacc[0] = full denominator for query lr.
    const float rinv = 1.0f / dacc[0];

    // O^T C-layout: (e = nt*16+quad*4+r, q = lr) -> packed ushort4 stores
    const long orow = rowbase + qb + lr;
#pragma unroll
    for (int nt = 0; nt < 4; nt++) {
        ushort4 ov = {f2b(oacc[nt][0] * rinv), f2b(oacc[nt][1] * rinv),
                      f2b(oacc[nt][2] * rinv), f2b(oacc[nt][3] * rinv)};
        *(ushort4*)&o[orow * 1024 + h * 64 + nt * 16 + quad * 4] = ov;
    }
#undef STAGE
}

// ---------------------------------------------------------------------------
// LayerNorm over last dim (1024), bf16 in, OT out, fp32 stats/params.
// ---------------------------------------------------------------------------
__device__ __forceinline__ void st4(float* p, float a, float b, float c, float d) {
    float4 v = {a, b, c, d};
    *(float4*)p = v;
}
__device__ __forceinline__ void st4(unsigned short* p, float a, float b, float c,
                                    float d) {
    ushort4 v = {f2b(a), f2b(b), f2b(c), f2b(d)};
    *(ushort4*)p = v;
}

template <typename OT>
__global__ __launch_bounds__(256) void ln_kernel(
    const unsigned short* __restrict__ in, const float* __restrict__ g,
    const float* __restrict__ b, OT* __restrict__ out) {
    __shared__ float red[4];
    const long row = blockIdx.x;
    const int tid = threadIdx.x;
    ushort4 u = *(const ushort4*)&in[row * 1024 + tid * 4];
    float v[4] = {b2f(u.x), b2f(u.y), b2f(u.z), b2f(u.w)};
    float s = v[0] + v[1] + v[2] + v[3];
#pragma unroll
    for (int off = 32; off > 0; off >>= 1) s += __shfl_down(s, off, 64);
    if ((tid & 63) == 0) red[tid >> 6] = s;
    __syncthreads();
    const float mu = (red[0] + red[1] + red[2] + red[3]) * (1.0f / 1024.0f);
    __syncthreads();
    float d[4], sq = 0.f;
#pragma unroll
    for (int i = 0; i < 4; i++) { d[i] = v[i] - mu; sq += d[i] * d[i]; }
#pragma unroll
    for (int off = 32; off > 0; off >>= 1) sq += __shfl_down(sq, off, 64);
    if ((tid & 63) == 0) red[tid >> 6] = sq;
    __syncthreads();
    const float var = (red[0] + red[1] + red[2] + red[3]) * (1.0f / 1024.0f);
    const float rs = rsqrtf(var + 1e-5f);
    float4 gu = *(const float4*)&g[tid * 4];
    float4 bu = *(const float4*)&b[tid * 4];
    st4(&out[row * 1024 + tid * 4], d[0] * rs * gu.x + bu.x,
        d[1] * rs * gu.y + bu.y, d[2] * rs * gu.z + bu.z,
        d[3] * rs * gu.w + bu.w);
}

// ---------------------------------------------------------------------------
extern "C" void kernel_launch(void* const* d_in, const int* in_sizes, int n_in,
                              void* d_out, int out_size, void* d_ws, size_t ws_size,
                              hipStream_t stream) {
    (void)in_sizes; (void)n_in; (void)out_size; (void)ws_size;
    const float* x   = (const float*)d_in[0];
    const float* wq  = (const float*)d_in[1];
    const float* bq  = (const float*)d_in[2];
    const float* wk  = (const float*)d_in[3];
    const float* bk  = (const float*)d_in[4];
    const float* wv  = (const float*)d_in[5];
    const float* bv  = (const float*)d_in[6];
    const float* wo  = (const float*)d_in[7];
    const float* bo  = (const float*)d_in[8];
    const float* g1  = (const float*)d_in[9];
    const float* be1 = (const float*)d_in[10];
    const float* w1  = (const float*)d_in[11];
    const float* b1  = (const float*)d_in[12];
    const float* w2  = (const float*)d_in[13];
    const float* b2  = (const float*)d_in[14];
    const float* g2  = (const float*)d_in[15];
    const float* be2 = (const float*)d_in[16];

    // Workspace (bf16 unless noted), high-water 153 MB:
    // [0,24) weight T  [24,25) BQKV fp32  [25,41) XB->R1  [41,89) QKV->Y,R2
    // [73,137) Hb  [89,105) O  [137,153) VT
    char* ws = (char*)d_ws;
    const size_t MB = 1024 * 1024;
    unsigned short* WT_QKV = (unsigned short*)(ws + 0);        // [3072,1024]
    unsigned short* WT_O   = (unsigned short*)(ws + 6 * MB);   // [1024,1024]
    unsigned short* WT_1   = (unsigned short*)(ws + 8 * MB);   // [4096,1024]
    unsigned short* WT_2   = (unsigned short*)(ws + 16 * MB);  // [1024,4096]
    float*          BQKV   = (float*)(ws + 24 * MB);           // [3072]
    unsigned short* XB     = (unsigned short*)(ws + 25 * MB);  // [8192,1024]
    unsigned short* QKV    = (unsigned short*)(ws + 41 * MB);  // [8192,3072]
    unsigned short* O      = (unsigned short*)(ws + 89 * MB);  // [8192,1024]
    unsigned short* R1     = (unsigned short*)(ws + 25 * MB);  // over dead XB
    unsigned short* Y      = (unsigned short*)(ws + 41 * MB);  // over dead QKV
    unsigned short* R2     = (unsigned short*)(ws + 57 * MB);  // over dead QKV
    unsigned short* Hb     = (unsigned short*)(ws + 73 * MB);  // [8192,4096]
    unsigned short* VT     = (unsigned short*)(ws + 137 * MB); // [64,64,2048]
    float*          OUT    = (float*)d_out;

    const dim3 tb(32, 8, 1);
    transpose_f2b<<<dim3(2, 32, 16), tb, 0, stream>>>(wq, WT_QKV, 1024, 64, 65536L, 0, 1024);
    transpose_f2b<<<dim3(2, 32, 16), tb, 0, stream>>>(wk, WT_QKV, 1024, 64, 65536L, 1024, 1024);
    transpose_f2b<<<dim3(2, 32, 16), tb, 0, stream>>>(wv, WT_QKV, 1024, 64, 65536L, 2048, 1024);
    transpose_f2b<<<dim3(32, 32, 1), tb, 0, stream>>>(wo, WT_O, 1024, 1024, 0L, 0, 1024);
    transpose_f2b<<<dim3(128, 32, 1), tb, 0, stream>>>(w1, WT_1, 1024, 4096, 0L, 0, 1024);
    transpose_f2b<<<dim3(32, 128, 1), tb, 0, stream>>>(w2, WT_2, 4096, 1024, 0L, 0, 4096);
    concat_bias<<<dim3(12), 256, 0, stream>>>(bq, bk, bv, BQKV);
    f2b_bulk<<<dim3(4096), 256, 0, stream>>>(x, XB);

    // QKV projection (Q cols pre-scaled by QSCALE via op=2)
    gemm_bt<unsigned short><<<dim3(24, 64), 256, 0, stream>>>(
        XB, WT_QKV, QKV, BQKV, (const unsigned short*)nullptr, 8192, 3072, 1024, 2);
    // V^T per head -> VT
    transpose_v<<<dim3(64, 2, 64), tb, 0, stream>>>(QKV, VT);
    // Flash attention -> O
    attn_kernel<<<dim3(2048), 256, 0, stream>>>(QKV, VT, O);
    // Out-proj + bo + residual x(fp32) -> R1
    gemm_bt<float><<<dim3(8, 64), 256, 0, stream>>>(
        O, WT_O, R1, bo, x, 8192, 1024, 1024, 0);
    // LN1 -> Y
    ln_kernel<unsigned short><<<dim3(8192), 256, 0, stream>>>(R1, g1, be1, Y);
    // FF1 + b1 + ReLU -> Hb
    gemm_bt<unsigned short><<<dim3(32, 64), 256, 0, stream>>>(
        Y, WT_1, Hb, b1, (const unsigned short*)nullptr, 8192, 4096, 1024, 1);
    // FF2 + b2 + residual Y -> R2
    gemm_bt<unsigned short><<<dim3(8, 64), 256, 0, stream>>>(
        Hb, WT_2, R2, b2, Y, 8192, 1024, 4096, 0);
    // LN2 -> out (fp32)
    ln_kernel<float><<<dim3(8192), 256, 0, stream>>>(R2, g2, be2, OUT);
}

// Round 4
// 613.447 us; speedup vs baseline: 1.2108x; 1.2108x over previous
//
#include <hip/hip_runtime.h>
#include <stdint.h>

// Inputs/outputs fp32; internal compute bf16 MFMA + fp32 accumulate.
// B=4 S=2048 D=1024 H=16 DH=64 F=4096; M = B*S = 8192.

typedef short bf16x8 __attribute__((ext_vector_type(8)));
typedef unsigned short u16x8 __attribute__((ext_vector_type(8)));
typedef float f32x4 __attribute__((ext_vector_type(4)));
typedef unsigned int u32x2 __attribute__((ext_vector_type(2)));

#define MFMA16(a, b, c) __builtin_amdgcn_mfma_f32_16x16x32_bf16((a), (b), (c), 0, 0, 0)

// 0.125 (1/sqrt(64)) / ln(2): folded into Q so softmax runs in exp2 domain.
#define QSCALE 0.1803368801111204f

__device__ __forceinline__ float b2f(unsigned short u) {
    union { unsigned u32; float f; } x;
    x.u32 = ((unsigned)u) << 16;
    return x.f;
}
__device__ __forceinline__ unsigned short f2b(float f) {
    union { float f; unsigned u; } x;
    x.f = f;
    unsigned r = x.u + 0x7fff + ((x.u >> 16) & 1);  // RNE
    return (unsigned short)(r >> 16);
}

// async 16B global -> LDS (wave-uniform LDS base + lane*16 dest semantics)
__device__ __forceinline__ void gl16(const unsigned short* g, unsigned short* l) {
    __builtin_amdgcn_global_load_lds(
        (__attribute__((address_space(1))) unsigned int*)(unsigned long)g,
        (__attribute__((address_space(3))) unsigned int*)l, 16, 0, 0);
}

// ---------------------------------------------------------------------------
// fp32 -> bf16 bulk convert (8 elems/thread)
// ---------------------------------------------------------------------------
__global__ __launch_bounds__(256) void f2b_bulk(const float* __restrict__ in,
                                                unsigned short* __restrict__ out) {
    const long i = ((long)blockIdx.x * 256 + threadIdx.x) * 8;
    float4 a = *(const float4*)&in[i];
    float4 b = *(const float4*)&in[i + 4];
    u16x8 u;
    u[0] = f2b(a.x); u[1] = f2b(a.y); u[2] = f2b(a.z); u[3] = f2b(a.w);
    u[4] = f2b(b.x); u[5] = f2b(b.y); u[6] = f2b(b.z); u[7] = f2b(b.w);
    *(u16x8*)&out[i] = u;
}

// ---------------------------------------------------------------------------
// Tiled transpose fp32 -> bf16: out[(row0+batch*C+c)*out_ld + r] = in[b][r][c]
// ---------------------------------------------------------------------------
__global__ void transpose_f2b(const float* __restrict__ in,
                              unsigned short* __restrict__ out,
                              int R, int C, long in_batch_stride,
                              int out_row0, int out_ld) {
    __shared__ float tile[32][33];
    const int batch = blockIdx.z;
    const float* src = in + (long)batch * in_batch_stride;
    const int c0 = blockIdx.x * 32, r0 = blockIdx.y * 32;
    const int tx = threadIdx.x, ty = threadIdx.y;  // (32, 8)
#pragma unroll
    for (int i = 0; i < 32; i += 8)
        tile[ty + i][tx] = src[(long)(r0 + ty + i) * C + c0 + tx];
    __syncthreads();
#pragma unroll
    for (int i = 0; i < 32; i += 8)
        out[(long)(out_row0 + batch * C + c0 + ty + i) * out_ld + r0 + tx] =
            f2b(tile[tx][ty + i]);
}

// ---------------------------------------------------------------------------
// V^T builder: vt[(bh*64 + e)*2048 + s] = qkv[(b*2048+s)*3072 + 2048 + h*64 + e]
// ---------------------------------------------------------------------------
__global__ void transpose_v(const unsigned short* __restrict__ qkv,
                            unsigned short* __restrict__ vt) {
    __shared__ unsigned short tile[32][33];
    const int bh = blockIdx.z;
    const int b = bh >> 4, h = bh & 15;
    const int s0 = blockIdx.x * 32, e0 = blockIdx.y * 32;
    const int tx = threadIdx.x, ty = threadIdx.y;  // (32, 8)
    const unsigned short* src = qkv + ((long)b * 2048) * 3072 + 2048 + h * 64;
#pragma unroll
    for (int i = 0; i < 32; i += 8)
        tile[ty + i][tx] = src[(long)(s0 + ty + i) * 3072 + e0 + tx];
    __syncthreads();
    unsigned short* dst = vt + ((long)bh * 64) * 2048;
#pragma unroll
    for (int i = 0; i < 32; i += 8)
        dst[(long)(e0 + ty + i) * 2048 + s0 + tx] = tile[tx][ty + i];
}

__global__ void concat_bias(const float* __restrict__ bq,
                            const float* __restrict__ bk,
                            const float* __restrict__ bv,
                            float* __restrict__ out) {
    int n = blockIdx.x * 256 + threadIdx.x;  // 0..3071
    out[n] = (n < 1024) ? bq[n] : (n < 2048) ? bk[n - 1024] : bv[n - 2048];
}

__device__ __forceinline__ float to_f(float v) { return v; }
__device__ __forceinline__ float to_f(unsigned short v) { return b2f(v); }

// ---------------------------------------------------------------------------
// gemm_ring: C[M,N] = A[M,K] @ Bt[N,K]^T (bf16), fp32 accum, bf16 out.
// Counted-vmcnt ring pipeline (T3/T4): K is processed in 32-wide half-steps,
// each staged into one slot of a 4-deep LDS ring (A[4][256][32]+B[4][128][32]
// = 96 KB). Steady state keeps 3 stages (9 gl16) in flight; the per-step
// barrier is preceded by s_waitcnt vmcnt(6) -- never a drain to 0 in the
// main loop, so staging latency hides under ~2 half-steps of MFMA. Tail
// peels to vmcnt(3)/vmcnt(0). Race audit: step s reads slot s%4; stage s+3
// (issued after step-s barrier) writes slot (s-1)%4, whose readers all
// passed that barrier; per-wave vmcnt certifies each wave's own slices and
// the barrier makes it collective.
// 512 threads = 8 waves (4M x 2N), per-wave C = 64x64, acc[4][4].
// LDS rows are 64 B ([.][32]): 64-lane ds_read_b128 sits at the bank-BW
// floor (16 rows x 64 B window == 1 KB request) -- no swizzle needed.
// op: 0 none, 1 ReLU, 2 scale cols<1024 by QSCALE (QKV gemm: pre-scale Q).
// ---------------------------------------------------------------------------
template <typename RT>
__global__ __launch_bounds__(512, 2) void gemm_ring(
    const unsigned short* __restrict__ A, const unsigned short* __restrict__ Bt,
    unsigned short* __restrict__ C, const float* __restrict__ bias,
    const RT* __restrict__ resid, int M, int N, int K, int op) {
    __shared__ __align__(16) unsigned short As[4][256 * 32];  // 64 KB
    __shared__ __align__(16) unsigned short Bs[4][128 * 32];  // 32 KB
    const int tid = threadIdx.x;
    const int wave = tid >> 6, lane = tid & 63;
    const int quad = lane >> 4, lr = lane & 15;
    const int wm = wave >> 1, wn = wave & 1;  // 4 x 2 wave grid

    // XCD-aware bijective block swizzle (all grids have nwg % 8 == 0).
    const int nwg = gridDim.x * gridDim.y;
    const int orig = blockIdx.y * gridDim.x + blockIdx.x;
    const int wg = (orig & 7) * (nwg >> 3) + (orig >> 3);
    const long n0 = (long)(wg % gridDim.x) * 128;
    const long m0 = (long)(wg / gridDim.x) * 256;

    f32x4 acc[4][4] = {};

    // Staging geometry (per wave, per half-step): A = 2 gl16 (32 rows x 32
    // cols), B = 1 gl16 (16 rows x 32 cols). gl16 covers 16 rows x 64 B:
    // lane row = lane>>2, col chunk = (lane&3)*8.
    const unsigned short* gA =
        A + (m0 + wave * 32 + (lane >> 2)) * (long)K + (lane & 3) * 8;
    const unsigned short* gB =
        Bt + (n0 + wave * 16 + (lane >> 2)) * (long)K + (lane & 3) * 8;
    const long rstep = 16 * (long)K;
    unsigned short* const lA0 = &As[0][wave * 32 * 32];
    unsigned short* const lA1 = &As[0][(wave * 32 + 16) * 32];
    unsigned short* const lB0 = &Bs[0][wave * 16 * 32];

#define RSTAGE(si)                                                  \
    {                                                               \
        const int _sl = (si) & 3;                                   \
        const long _kc = (long)(si) * 32;                           \
        gl16(gA + _kc, lA0 + _sl * 8192);                           \
        gl16(gA + rstep + _kc, lA1 + _sl * 8192);                   \
        gl16(gB + _kc, lB0 + _sl * 4096);                           \
    }

    const int S = K >> 5;  // 32-wide half-steps
    RSTAGE(0);
    RSTAGE(1);
    RSTAGE(2);

    for (int s = 0; s < S; ++s) {
        if (s + 2 < S) {
            asm volatile("s_waitcnt vmcnt(6)" ::: "memory");
        } else if (s + 1 < S) {
            asm volatile("s_waitcnt vmcnt(3)" ::: "memory");
        } else {
            asm volatile("s_waitcnt vmcnt(0)" ::: "memory");
        }
        __builtin_amdgcn_s_barrier();
        const int slot = s & 3;
        bf16x8 af[4], bfr[4];
#pragma unroll
        for (int mi = 0; mi < 4; mi++)
            af[mi] = *(const bf16x8*)&As[slot][(wm * 64 + mi * 16 + lr) * 32 + quad * 8];
#pragma unroll
        for (int ni = 0; ni < 4; ni++)
            bfr[ni] = *(const bf16x8*)&Bs[slot][(wn * 64 + ni * 16 + lr) * 32 + quad * 8];
#pragma unroll
        for (int mi = 0; mi < 4; mi++)
#pragma unroll
            for (int ni = 0; ni < 4; ni++)
                acc[mi][ni] = MFMA16(af[mi], bfr[ni], acc[mi][ni]);
        if (s + 3 < S) RSTAGE(s + 3);
    }
#undef RSTAGE

#pragma unroll
    for (int ni = 0; ni < 4; ni++) {
        const long col = n0 + wn * 64 + ni * 16 + lr;
        const float bv = bias ? bias[col] : 0.0f;
        const float cscale = (op == 2 && col < 1024) ? QSCALE : 1.0f;
#pragma unroll
        for (int mi = 0; mi < 4; mi++) {
#pragma unroll
            for (int r = 0; r < 4; r++) {
                const long row = m0 + wm * 64 + mi * 16 + quad * 4 + r;
                float v = (acc[mi][ni][r] + bv) * cscale;
                if (resid) v += to_f(resid[row * (long)N + col]);
                if (op == 1) v = fmaxf(v, 0.0f);
                C[row * (long)N + col] = f2b(v);
            }
        }
    }
}

// ---------------------------------------------------------------------------
// Flash attention v7 (transposed-S; K/V LDS-staged XOR-swizzled; NO-MAX
// softmax; in-register P^T redistribution via permlane swaps; ones-MFMA
// denominator). [v8's global-V experiment regressed 2x -- L2 latency landed
// serially in the PV critical path -- reverted to the measured-133us v7.]
// ---------------------------------------------------------------------------
__global__ __launch_bounds__(256, 5) void attn_kernel(
    const unsigned short* __restrict__ qkv, const unsigned short* __restrict__ vt,
    unsigned short* __restrict__ o) {
    __shared__ __align__(16) unsigned short Klds[2][64 * 64];  // 16 KB
    __shared__ __align__(16) unsigned short Vlds[2][64 * 64];  // 16 KB
    // Block swizzle: all 32 q-tiles of one (b,h) share l%8 -> same XCD.
    const int l = blockIdx.x;
    const int bh = ((l >> 8) << 3) | (l & 7);
    const int qt = (l >> 3) & 31;
    const int b = bh >> 4, h = bh & 15;
    const int tid = threadIdx.x;
    const int wave = tid >> 6, lane = tid & 63;
    const int quad = lane >> 4, lr = lane & 15;
    const long rowbase = (long)b * 2048;
    const int qb = qt * 64 + wave * 16;

    // Q fragments (B operand; n = query = lr), register-resident
    bf16x8 q0, q1;
    {
        const unsigned short* qrow = qkv + (rowbase + qb + lr) * 3072 + h * 64;
        q0 = *(const bf16x8*)&qrow[quad * 8];
        q1 = *(const bf16x8*)&qrow[32 + quad * 8];
    }

    // all-ones bf16 A-fragment for the denominator MFMA
    bf16x8 ones;
#pragma unroll
    for (int i = 0; i < 8; i++) ones[i] = (short)0x3F80;

    // Staging: wave w stages rows [w*16, w*16+16) of the K and V tiles via
    // 2 gl16 each. Lane: row = base + (lane>>3), dst chunk = lane&7,
    // src chunk = (lane&7) ^ (row&7)  [row&7 == lane>>3 here].
    const int srow = lane >> 3;
    const int sxc = (lane & 7) ^ srow;
    const unsigned short* kp =
        qkv + (rowbase + wave * 16 + srow) * 3072 + 1024 + h * 64 + sxc * 8;
    const unsigned short* vp =
        vt + ((long)bh * 64 + wave * 16 + srow) * 2048 + sxc * 8;
    const long KADV = 64L * 3072;  // next key-tile (rows)
    unsigned short* const kd0 = &Klds[0][wave * 16 * 64];
    unsigned short* const vd0 = &Vlds[0][wave * 16 * 64];

#define STAGE(bf)                                                     \
    {                                                                 \
        gl16(kp, kd0 + (bf)*4096);                                    \
        gl16(kp + 8 * 3072, kd0 + (bf)*4096 + 8 * 64);                \
        gl16(vp, vd0 + (bf)*4096);                                    \
        gl16(vp + 8 * 2048, vd0 + (bf)*4096 + 8 * 64);                \
    }

    f32x4 oacc[4] = {};
    f32x4 dacc = {};  // denominator accumulator (all rows identical)

    // swizzled chunk offsets for A-operand reads (row&7 == lr&7)
    const int x7 = lr & 7;
    const int c00 = (quad ^ x7) * 8;        // kc=0
    const int c01 = ((4 | quad) ^ x7) * 8;  // kc=1

    STAGE(0);
    __syncthreads();

    for (int kt = 0; kt < 32; kt++) {
        const int buf = kt & 1;
        if (kt < 31) {
            kp += KADV;
            vp += 64;
            STAGE(buf ^ 1);
        }
        // S^T = K·Q^T  (A = K tile rows, k-dim = dh)
        const unsigned short* kb = &Klds[buf][0];
        f32x4 s4[4];
#pragma unroll
        for (int nt = 0; nt < 4; nt++) {
            const unsigned short* krow = kb + (nt * 16 + lr) * 64;
            bf16x8 k0 = *(const bf16x8*)&krow[c00];
            bf16x8 k1 = *(const bf16x8*)&krow[c01];
            f32x4 z = {};
            z = MFMA16(k0, q0, z);
            z = MFMA16(k1, q1, z);
            s4[nt] = z;
        }
        // p = exp2(s) unnormalized; pack pairs to bf16 (v_cvt_pk, RNE).
        // pwv[nt][tl] holds keys (nt*16 + quad*4 + 2*tl, +1) for query lr.
        unsigned pwv[4][2];
#pragma unroll
        for (int nt = 0; nt < 4; nt++) {
            float p0 = exp2f(s4[nt][0]);
            float p1 = exp2f(s4[nt][1]);
            float p2 = exp2f(s4[nt][2]);
            float p3 = exp2f(s4[nt][3]);
            asm("v_cvt_pk_bf16_f32 %0, %1, %2"
                : "=v"(pwv[nt][0]) : "v"(p0), "v"(p1));
            asm("v_cvt_pk_bf16_f32 %0, %1, %2"
                : "=v"(pwv[nt][1]) : "v"(p2), "v"(p3));
        }
        // In-register P^T quad redistribution (permlane swaps).
        // Stage 1: pairs over reg-bit k4 = nt&1: permlane32_swap.
        // Stage 2: pairs over reg-bit k3: permlane16_swap.
        // Result pq[kc][t]: keys (kc*32 + quad*8 + 2t, +1) for query lr —
        // exactly the 16x16x32 B-operand fragment for PV.
        unsigned pq[2][4];
#pragma unroll
        for (int kc = 0; kc < 2; kc++)
#pragma unroll
            for (int tl = 0; tl < 2; tl++) {
                u32x2 y = __builtin_amdgcn_permlane32_swap(
                    pwv[2 * kc][tl], pwv[2 * kc + 1][tl], false, false);
                u32x2 z = __builtin_amdgcn_permlane16_swap(y[0], y[1], false, false);
                pq[kc][tl] = z[0];
                pq[kc][2 + tl] = z[1];
            }

        // O^T += V^T·P^T  (A = V^T tile rows = dh, k-dim = keys)
        // + denominator row-sum on the matrix pipe (A = ones).
        const unsigned short* vb = &Vlds[buf][0];
#pragma unroll
        for (int kc = 0; kc < 2; kc++) {
            union { unsigned u[4]; bf16x8 h; } pu;
            pu.u[0] = pq[kc][0]; pu.u[1] = pq[kc][1];
            pu.u[2] = pq[kc][2]; pu.u[3] = pq[kc][3];
            const int vc = kc ? c01 : c00;
            dacc = MFMA16(ones, pu.h, dacc);
#pragma unroll
            for (int nt = 0; nt < 4; nt++) {
                bf16x8 va = *(const bf16x8*)&vb[(nt * 16 + lr) * 64 + vc];
                oacc[nt] = MFMA16(va, pu.h, oacc[nt]);
            }
        }
        __syncthreads();  // buf readers done + buf^1 staging drained (vmcnt)
    }

    // dacc rows are identical: dacc[0] = full denominator for query lr.
    const float rinv = 1.0f / dacc[0];

    // O^T C-layout: (e = nt*16+quad*4+r, q = lr) -> packed ushort4 stores
    const long orow = rowbase + qb + lr;
#pragma unroll
    for (int nt = 0; nt < 4; nt++) {
        ushort4 ov = {f2b(oacc[nt][0] * rinv), f2b(oacc[nt][1] * rinv),
                      f2b(oacc[nt][2] * rinv), f2b(oacc[nt][3] * rinv)};
        *(ushort4*)&o[orow * 1024 + h * 64 + nt * 16 + quad * 4] = ov;
    }
#undef STAGE
}

// ---------------------------------------------------------------------------
// LayerNorm over last dim (1024), bf16 in, OT out, fp32 stats/params.
// ---------------------------------------------------------------------------
__device__ __forceinline__ void st4(float* p, float a, float b, float c, float d) {
    float4 v = {a, b, c, d};
    *(float4*)p = v;
}
__device__ __forceinline__ void st4(unsigned short* p, float a, float b, float c,
                                    float d) {
    ushort4 v = {f2b(a), f2b(b), f2b(c), f2b(d)};
    *(ushort4*)p = v;
}

template <typename OT>
__global__ __launch_bounds__(256) void ln_kernel(
    const unsigned short* __restrict__ in, const float* __restrict__ g,
    const float* __restrict__ b, OT* __restrict__ out) {
    __shared__ float red[4];
    const long row = blockIdx.x;
    const int tid = threadIdx.x;
    ushort4 u = *(const ushort4*)&in[row * 1024 + tid * 4];
    float v[4] = {b2f(u.x), b2f(u.y), b2f(u.z), b2f(u.w)};
    float s = v[0] + v[1] + v[2] + v[3];
#pragma unroll
    for (int off = 32; off > 0; off >>= 1) s += __shfl_down(s, off, 64);
    if ((tid & 63) == 0) red[tid >> 6] = s;
    __syncthreads();
    const float mu = (red[0] + red[1] + red[2] + red[3]) * (1.0f / 1024.0f);
    __syncthreads();
    float d[4], sq = 0.f;
#pragma unroll
    for (int i = 0; i < 4; i++) { d[i] = v[i] - mu; sq += d[i] * d[i]; }
#pragma unroll
    for (int off = 32; off > 0; off >>= 1) sq += __shfl_down(sq, off, 64);
    if ((tid & 63) == 0) red[tid >> 6] = sq;
    __syncthreads();
    const float var = (red[0] + red[1] + red[2] + red[3]) * (1.0f / 1024.0f);
    const float rs = rsqrtf(var + 1e-5f);
    float4 gu = *(const float4*)&g[tid * 4];
    float4 bu = *(const float4*)&b[tid * 4];
    st4(&out[row * 1024 + tid * 4], d[0] * rs * gu.x + bu.x,
        d[1] * rs * gu.y + bu.y, d[2] * rs * gu.z + bu.z,
        d[3] * rs * gu.w + bu.w);
}

// ---------------------------------------------------------------------------
extern "C" void kernel_launch(void* const* d_in, const int* in_sizes, int n_in,
                              void* d_out, int out_size, void* d_ws, size_t ws_size,
                              hipStream_t stream) {
    (void)in_sizes; (void)n_in; (void)out_size; (void)ws_size;
    const float* x   = (const float*)d_in[0];
    const float* wq  = (const float*)d_in[1];
    const float* bq  = (const float*)d_in[2];
    const float* wk  = (const float*)d_in[3];
    const float* bk  = (const float*)d_in[4];
    const float* wv  = (const float*)d_in[5];
    const float* bv  = (const float*)d_in[6];
    const float* wo  = (const float*)d_in[7];
    const float* bo  = (const float*)d_in[8];
    const float* g1  = (const float*)d_in[9];
    const float* be1 = (const float*)d_in[10];
    const float* w1  = (const float*)d_in[11];
    const float* b1  = (const float*)d_in[12];
    const float* w2  = (const float*)d_in[13];
    const float* b2  = (const float*)d_in[14];
    const float* g2  = (const float*)d_in[15];
    const float* be2 = (const float*)d_in[16];

    // Workspace (bf16 unless noted), high-water 153 MB:
    // [0,24) weight T  [24,25) BQKV fp32  [25,41) XB->R1  [41,89) QKV->Y,R2
    // [73,137) Hb  [89,105) O  [137,153) VT
    char* ws = (char*)d_ws;
    const size_t MB = 1024 * 1024;
    unsigned short* WT_QKV = (unsigned short*)(ws + 0);        // [3072,1024]
    unsigned short* WT_O   = (unsigned short*)(ws + 6 * MB);   // [1024,1024]
    unsigned short* WT_1   = (unsigned short*)(ws + 8 * MB);   // [4096,1024]
    unsigned short* WT_2   = (unsigned short*)(ws + 16 * MB);  // [1024,4096]
    float*          BQKV   = (float*)(ws + 24 * MB);           // [3072]
    unsigned short* XB     = (unsigned short*)(ws + 25 * MB);  // [8192,1024]
    unsigned short* QKV    = (unsigned short*)(ws + 41 * MB);  // [8192,3072]
    unsigned short* O      = (unsigned short*)(ws + 89 * MB);  // [8192,1024]
    unsigned short* R1     = (unsigned short*)(ws + 25 * MB);  // over dead XB
    unsigned short* Y      = (unsigned short*)(ws + 41 * MB);  // over dead QKV
    unsigned short* R2     = (unsigned short*)(ws + 57 * MB);  // over dead QKV
    unsigned short* Hb     = (unsigned short*)(ws + 73 * MB);  // [8192,4096]
    unsigned short* VT     = (unsigned short*)(ws + 137 * MB); // [64,64,2048]
    float*          OUT    = (float*)d_out;

    const dim3 tb(32, 8, 1);
    transpose_f2b<<<dim3(2, 32, 16), tb, 0, stream>>>(wq, WT_QKV, 1024, 64, 65536L, 0, 1024);
    transpose_f2b<<<dim3(2, 32, 16), tb, 0, stream>>>(wk, WT_QKV, 1024, 64, 65536L, 1024, 1024);
    transpose_f2b<<<dim3(2, 32, 16), tb, 0, stream>>>(wv, WT_QKV, 1024, 64, 65536L, 2048, 1024);
    transpose_f2b<<<dim3(32, 32, 1), tb, 0, stream>>>(wo, WT_O, 1024, 1024, 0L, 0, 1024);
    transpose_f2b<<<dim3(128, 32, 1), tb, 0, stream>>>(w1, WT_1, 1024, 4096, 0L, 0, 1024);
    transpose_f2b<<<dim3(32, 128, 1), tb, 0, stream>>>(w2, WT_2, 4096, 1024, 0L, 0, 4096);
    concat_bias<<<dim3(12), 256, 0, stream>>>(bq, bk, bv, BQKV);
    f2b_bulk<<<dim3(4096), 256, 0, stream>>>(x, XB);

    // QKV projection (Q cols pre-scaled by QSCALE via op=2)
    gemm_ring<unsigned short><<<dim3(24, 32), 512, 0, stream>>>(
        XB, WT_QKV, QKV, BQKV, (const unsigned short*)nullptr, 8192, 3072, 1024, 2);
    // V^T per head -> VT
    transpose_v<<<dim3(64, 2, 64), tb, 0, stream>>>(QKV, VT);
    // Flash attention -> O
    attn_kernel<<<dim3(2048), 256, 0, stream>>>(QKV, VT, O);
    // Out-proj + bo + residual x(fp32) -> R1
    gemm_ring<float><<<dim3(8, 32), 512, 0, stream>>>(
        O, WT_O, R1, bo, x, 8192, 1024, 1024, 0);
    // LN1 -> Y
    ln_kernel<unsigned short><<<dim3(8192), 256, 0, stream>>>(R1, g1, be1, Y);
    // FF1 + b1 + ReLU -> Hb
    gemm_ring<unsigned short><<<dim3(32, 32), 512, 0, stream>>>(
        Y, WT_1, Hb, b1, (const unsigned short*)nullptr, 8192, 4096, 1024, 1);
    // FF2 + b2 + residual Y -> R2
    gemm_ring<unsigned short><<<dim3(8, 32), 512, 0, stream>>>(
        Hb, WT_2, R2, b2, Y, 8192, 1024, 4096, 0);
    // LN2 -> out (fp32)
    ln_kernel<float><<<dim3(8192), 256, 0, stream>>>(R2, g2, be2, OUT);
}